// Round 2
// baseline (1035.800 us; speedup 1.0000x reference)
//
#include <hip/hip_runtime.h>

// Problem constants (from reference)
#define B_TREES 32
#define DEPTH   12
#define M_NODES 4095                  // 2^12 - 1
#define N_NODES (B_TREES * M_NODES)   // 131040
#define HDIM    256
#define VOCAB   32000
#define NCLS    20
#define MAXROWS 65536                 // largest level (leaves): 32 * 2048

typedef _Float16 f16;
typedef _Float16 f16x8 __attribute__((ext_vector_type(8)));
typedef _Float16 f16x4 __attribute__((ext_vector_type(4)));
typedef float    f32x4 __attribute__((ext_vector_type(4)));

__device__ __forceinline__ float sigf(float x)      { return 1.0f / (1.0f + __expf(-x)); }
__device__ __forceinline__ float tanh_fast(float x) { return 1.0f - 2.0f / (1.0f + __expf(2.0f * x)); }

// ---------------------------------------------------------------------------
// Init: convert the three weight matrices to fp16 (small: <1 MB total).
// ---------------------------------------------------------------------------
__global__ __launch_bounds__(256) void cvt_kernel(
    const float4* __restrict__ Wiou, const float4* __restrict__ Uiou,
    const float4* __restrict__ Uf,
    f16x4* __restrict__ Wiou16, f16x4* __restrict__ Uiou16,
    f16x4* __restrict__ Uf16)
{
    int i = blockIdx.x * 256 + threadIdx.x;   // in units of 4 floats
    if (i < 768 * HDIM / 4) {
        float4 v = Wiou[i];
        f16x4 r; r[0] = (f16)v.x; r[1] = (f16)v.y; r[2] = (f16)v.z; r[3] = (f16)v.w;
        Wiou16[i] = r;
        float4 u = Uiou[i];
        f16x4 s; s[0] = (f16)u.x; s[1] = (f16)u.y; s[2] = (f16)u.z; s[3] = (f16)u.w;
        Uiou16[i] = s;
    }
    if (i < HDIM * HDIM / 4) {
        float4 v = Uf[i];
        f16x4 r; r[0] = (f16)v.x; r[1] = (f16)v.y; r[2] = (f16)v.z; r[3] = (f16)v.w;
        Uf16[i] = r;
    }
}

// ---------------------------------------------------------------------------
// Leaf kernel: xiou = Emb[x] @ Wiou16^T (+b_iou), fused gate epilogue.
// 65536 leaf rows. Tile 128 rows x 64 cols, 4 waves, MFMA 16x16x32 f16.
// A fragment: row = lane&15, k0 = (lane>>4)*8 (8 contiguous k, converted
// from fp32 Emb inline).  C/D: col = lane&15, row = (lane>>4)*4 + reg.
// Writes h16 (node-indexed) and c_lvl (leaf-local row = b*2048 + t).
// ---------------------------------------------------------------------------
template <typename CT>
__global__ __launch_bounds__(256) void leaf_kernel(
    const int* __restrict__ x, const float* __restrict__ Emb,
    const f16* __restrict__ Wiou16, const float* __restrict__ b_iou,
    f16* __restrict__ h16, CT* __restrict__ c_lvl)
{
    const int lane = threadIdx.x & 63;
    const int w    = threadIdx.x >> 6;
    const int r0   = blockIdx.x * 128;
    const int cb0  = blockIdx.y * 64;
    const int qk   = (lane >> 4) * 8;
    const int l15  = lane & 15;

    int embBase[2];
    #pragma unroll
    for (int rf = 0; rf < 2; ++rf) {
        int row  = r0 + w * 32 + rf * 16 + l15;       // < 65536 (grid exact)
        int b    = row >> 11, t = row & 2047;
        int node = b * M_NODES + 2047 + t;
        embBase[rf] = x[node] * HDIM;
    }
    int wBase[3][4];
    #pragma unroll
    for (int mat = 0; mat < 3; ++mat)
        #pragma unroll
        for (int cf = 0; cf < 4; ++cf)
            wBase[mat][cf] = (mat * 256 + cb0 + cf * 16 + l15) * HDIM;

    f32x4 acc[3][2][4] = {};
    #pragma unroll
    for (int ks = 0; ks < 8; ++ks) {
        const int k0 = ks * 32 + qk;
        f16x8 a[2], bf[3][4];
        #pragma unroll
        for (int rf = 0; rf < 2; ++rf) {
            float4 v0 = *(const float4*)(Emb + embBase[rf] + k0);
            float4 v1 = *(const float4*)(Emb + embBase[rf] + k0 + 4);
            f16x8 av;
            av[0] = (f16)v0.x; av[1] = (f16)v0.y; av[2] = (f16)v0.z; av[3] = (f16)v0.w;
            av[4] = (f16)v1.x; av[5] = (f16)v1.y; av[6] = (f16)v1.z; av[7] = (f16)v1.w;
            a[rf] = av;
        }
        #pragma unroll
        for (int mat = 0; mat < 3; ++mat)
            #pragma unroll
            for (int cf = 0; cf < 4; ++cf)
                bf[mat][cf] = *(const f16x8*)(Wiou16 + wBase[mat][cf] + k0);
        #pragma unroll
        for (int mat = 0; mat < 3; ++mat)
            #pragma unroll
            for (int rf = 0; rf < 2; ++rf)
                #pragma unroll
                for (int cf = 0; cf < 4; ++cf)
                    acc[mat][rf][cf] = __builtin_amdgcn_mfma_f32_16x16x32_f16(
                        a[rf], bf[mat][cf], acc[mat][rf][cf], 0, 0, 0);
    }

    // Epilogue: leaves have h_sum = 0, fc_sum = 0.
    #pragma unroll
    for (int rf = 0; rf < 2; ++rf) {
        const int rbase = r0 + w * 32 + rf * 16 + (lane >> 4) * 4;
        #pragma unroll
        for (int cf = 0; cf < 4; ++cf) {
            const int col = cb0 + cf * 16 + l15;
            const float bi = b_iou[col], bo = b_iou[256 + col], bu = b_iou[512 + col];
            #pragma unroll
            for (int r = 0; r < 4; ++r) {
                int row  = rbase + r;                  // leaf-local row
                int b    = row >> 11, t = row & 2047;
                int node = b * M_NODES + 2047 + t;
                float i_ = acc[0][rf][cf][r] + bi;
                float o_ = acc[1][rf][cf][r] + bo;
                float u_ = acc[2][rf][cf][r] + bu;
                float c  = sigf(i_) * tanh_fast(u_);
                float h  = sigf(o_) * tanh_fast(c);
                c_lvl[row * HDIM + col]  = (CT)c;
                h16[node * HDIM + col]   = (f16)h;
            }
        }
    }
}

// ---------------------------------------------------------------------------
// Forget-gate kernel over child level lc: fc = sigmoid(h @ Uf^T + b_f) * c
// c_lvl/fc_lvl indexed by level-local row (b*2^lc + t); h16 node-indexed.
// ---------------------------------------------------------------------------
template <typename CT>
__global__ __launch_bounds__(256) void fgate_kernel(
    const f16* __restrict__ Uf16, const float* __restrict__ b_f,
    const f16* __restrict__ h16, const CT* __restrict__ c_lvl,
    CT* __restrict__ fc_lvl, int lc, int rows)
{
    const int lane = threadIdx.x & 63;
    const int w    = threadIdx.x >> 6;
    const int r0   = blockIdx.x * 128;
    const int cb0  = blockIdx.y * 64;
    const int qk   = (lane >> 4) * 8;
    const int l15  = lane & 15;
    const int mask = (1 << lc) - 1;

    int nodeBase[2];
    #pragma unroll
    for (int rf = 0; rf < 2; ++rf) {
        int row = r0 + w * 32 + rf * 16 + l15;
        if (row >= rows) row = rows - 1;
        int node = (row >> lc) * M_NODES + mask + (row & mask);
        nodeBase[rf] = node * HDIM;
    }
    int wBase[4];
    #pragma unroll
    for (int cf = 0; cf < 4; ++cf)
        wBase[cf] = (cb0 + cf * 16 + l15) * HDIM;

    f32x4 acc[2][4] = {};
    #pragma unroll
    for (int ks = 0; ks < 8; ++ks) {
        const int k0 = ks * 32 + qk;
        f16x8 a[2], bf[4];
        #pragma unroll
        for (int rf = 0; rf < 2; ++rf)
            a[rf] = *(const f16x8*)(h16 + nodeBase[rf] + k0);
        #pragma unroll
        for (int cf = 0; cf < 4; ++cf)
            bf[cf] = *(const f16x8*)(Uf16 + wBase[cf] + k0);
        #pragma unroll
        for (int rf = 0; rf < 2; ++rf)
            #pragma unroll
            for (int cf = 0; cf < 4; ++cf)
                acc[rf][cf] = __builtin_amdgcn_mfma_f32_16x16x32_f16(
                    a[rf], bf[cf], acc[rf][cf], 0, 0, 0);
    }

    #pragma unroll
    for (int rf = 0; rf < 2; ++rf) {
        const int rbase = r0 + w * 32 + rf * 16 + (lane >> 4) * 4;
        #pragma unroll
        for (int cf = 0; cf < 4; ++cf) {
            const int col = cb0 + cf * 16 + l15;
            const float bfv = b_f[col];
            #pragma unroll
            for (int r = 0; r < 4; ++r) {
                int row = rbase + r;
                if (row < rows) {
                    float f = sigf(acc[rf][cf][r] + bfv);
                    float c = (float)c_lvl[row * HDIM + col];
                    fc_lvl[row * HDIM + col] = (CT)(f * c);
                }
            }
        }
    }
}

// ---------------------------------------------------------------------------
// Level kernel (internal level l): iou = (h[c1]+h[c2]) @ Uiou^T + b_iou,
// c = sig(i)*tanh(u) + fc[2p]+fc[2p+1], h = sig(o)*tanh(c)
// Child level-local rows of parent-local row p are exactly 2p, 2p+1.
// ---------------------------------------------------------------------------
template <typename CT>
__global__ __launch_bounds__(256) void level_kernel(
    const f16* __restrict__ Uiou16, const float* __restrict__ b_iou,
    f16* __restrict__ h16, CT* __restrict__ c_lvl,
    const CT* __restrict__ fc_lvl, int l, int rows)
{
    const int lane = threadIdx.x & 63;
    const int w    = threadIdx.x >> 6;
    const int r0   = blockIdx.x * 128;
    const int cb0  = blockIdx.y * 64;
    const int qk   = (lane >> 4) * 8;
    const int l15  = lane & 15;
    const int mask = (1 << l) - 1;

    int childBase[2];
    #pragma unroll
    for (int rf = 0; rf < 2; ++rf) {
        int row = r0 + w * 32 + rf * 16 + l15;
        if (row >= rows) row = rows - 1;
        int b = row >> l, t = row & mask;
        int c1 = b * M_NODES + (2 << l) - 1 + 2 * t;   // left child node
        childBase[rf] = c1 * HDIM;
    }
    int wBase[3][4];
    #pragma unroll
    for (int mat = 0; mat < 3; ++mat)
        #pragma unroll
        for (int cf = 0; cf < 4; ++cf)
            wBase[mat][cf] = (mat * 256 + cb0 + cf * 16 + l15) * HDIM;

    f32x4 acc[3][2][4] = {};
    #pragma unroll
    for (int ks = 0; ks < 8; ++ks) {
        const int k0 = ks * 32 + qk;
        f16x8 a[2], bf[3][4];
        #pragma unroll
        for (int rf = 0; rf < 2; ++rf) {
            f16x8 a1 = *(const f16x8*)(h16 + childBase[rf] + k0);
            f16x8 a2 = *(const f16x8*)(h16 + childBase[rf] + HDIM + k0);
            a[rf] = a1 + a2;                       // child-sum of h (fp16)
        }
        #pragma unroll
        for (int mat = 0; mat < 3; ++mat)
            #pragma unroll
            for (int cf = 0; cf < 4; ++cf)
                bf[mat][cf] = *(const f16x8*)(Uiou16 + wBase[mat][cf] + k0);
        #pragma unroll
        for (int mat = 0; mat < 3; ++mat)
            #pragma unroll
            for (int rf = 0; rf < 2; ++rf)
                #pragma unroll
                for (int cf = 0; cf < 4; ++cf)
                    acc[mat][rf][cf] = __builtin_amdgcn_mfma_f32_16x16x32_f16(
                        a[rf], bf[mat][cf], acc[mat][rf][cf], 0, 0, 0);
    }

    #pragma unroll
    for (int rf = 0; rf < 2; ++rf) {
        const int rbase = r0 + w * 32 + rf * 16 + (lane >> 4) * 4;
        #pragma unroll
        for (int cf = 0; cf < 4; ++cf) {
            const int col = cb0 + cf * 16 + l15;
            const float bi = b_iou[col], bo = b_iou[256 + col], bu = b_iou[512 + col];
            #pragma unroll
            for (int r = 0; r < 4; ++r) {
                int row = rbase + r;                 // parent level-local row
                if (row < rows) {
                    int b = row >> l, t = row & mask;
                    int node = b * M_NODES + (1 << l) - 1 + t;
                    float fcs = (float)fc_lvl[(2 * row) * HDIM + col]
                              + (float)fc_lvl[(2 * row + 1) * HDIM + col];
                    float i_ = acc[0][rf][cf][r] + bi;
                    float o_ = acc[1][rf][cf][r] + bo;
                    float u_ = acc[2][rf][cf][r] + bu;
                    float c  = sigf(i_) * tanh_fast(u_) + fcs;
                    float h  = sigf(o_) * tanh_fast(c);
                    c_lvl[row * HDIM + col] = (CT)c;
                    h16[node * HDIM + col]  = (f16)h;
                }
            }
        }
    }
}

// ---------------------------------------------------------------------------
// Output: out = h_all @ W_out^T + b_out   [N, 20]
// ---------------------------------------------------------------------------
__global__ __launch_bounds__(256) void out_kernel(
    const f16* __restrict__ h16, const float* __restrict__ Wout,
    const float* __restrict__ bout, float* __restrict__ out)
{
    int row = blockIdx.x * 256 + threadIdx.x;
    if (row >= N_NODES) return;
    float acc[NCLS];
    #pragma unroll
    for (int c = 0; c < NCLS; ++c) acc[c] = bout[c];
    #pragma unroll 4
    for (int k = 0; k < HDIM; k += 8) {
        f16x8 hv = *(const f16x8*)(h16 + row * HDIM + k);
        float hf[8];
        #pragma unroll
        for (int j = 0; j < 8; ++j) hf[j] = (float)hv[j];
        #pragma unroll
        for (int c = 0; c < NCLS; ++c) {
            const float* wr = Wout + c * HDIM + k;   // wave-uniform → scalar loads
            #pragma unroll
            for (int j = 0; j < 8; ++j) acc[c] += hf[j] * wr[j];
        }
    }
    #pragma unroll
    for (int c = 0; c < NCLS; ++c) out[row * NCLS + c] = acc[c];
}

// ---------------------------------------------------------------------------
extern "C" void kernel_launch(void* const* d_in, const int* in_sizes, int n_in,
                              void* d_out, int out_size, void* d_ws, size_t ws_size,
                              hipStream_t stream)
{
    const int*   x     = (const int*)d_in[0];
    // d_in[1] = x_mask: leaf structure is static — folded into indexing.
    const float* Emb   = (const float*)d_in[2];
    const float* W_iou = (const float*)d_in[3];
    const float* b_iou = (const float*)d_in[4];
    const float* U_iou = (const float*)d_in[5];
    const float* U_f   = (const float*)d_in[6];
    const float* b_f   = (const float*)d_in[7];
    const float* W_out = (const float*)d_in[8];
    const float* b_out = (const float*)d_in[9];
    float* out = (float*)d_out;

    // Workspace budget: h16 (67.1 MB) + weights (0.92 MB) + 2 level buffers
    // (c, fc) at MAXROWS x 256: fp32 -> 134.2 MB (total ~202 MB),
    // fp16 -> 67.1 MB (total ~135 MB). Pick fp32 c/fc when it fits.
    const size_t fixed = (size_t)N_NODES * HDIM * 2 + (768 * HDIM * 2) * 2
                       + HDIM * HDIM * 2 + 4096;
    const size_t need32 = fixed + (size_t)MAXROWS * HDIM * 4 * 2;
    const bool use32 = ws_size >= need32;

    char* ws = (char*)d_ws;
    size_t off = 0;
    auto take = [&](size_t bytes) -> char* {
        char* p = ws + off; off += (bytes + 255) & ~(size_t)255; return p;
    };
    f16*   h16    = (f16*)take((size_t)N_NODES * HDIM * 2);
    size_t esz    = use32 ? 4 : 2;
    char*  c_buf  = take((size_t)MAXROWS * HDIM * esz);
    char*  fc_buf = take((size_t)MAXROWS * HDIM * esz);
    f16*   Wiou16 = (f16*)take((size_t)768 * HDIM * 2);
    f16*   Uiou16 = (f16*)take((size_t)768 * HDIM * 2);
    f16*   Uf16   = (f16*)take((size_t)HDIM * HDIM * 2);

    cvt_kernel<<<768 * HDIM / 4 / 256, 256, 0, stream>>>(
        (const float4*)W_iou, (const float4*)U_iou, (const float4*)U_f,
        (f16x4*)Wiou16, (f16x4*)Uiou16, (f16x4*)Uf16);

    if (use32) {
        float* c_lvl  = (float*)c_buf;
        float* fc_lvl = (float*)fc_buf;
        leaf_kernel<float><<<dim3(512, 4), 256, 0, stream>>>(
            x, Emb, Wiou16, b_iou, h16, c_lvl);
        for (int l = 10; l >= 0; --l) {
            int lc = l + 1;
            int rowsc = B_TREES << lc;
            int rowsp = B_TREES << l;
            fgate_kernel<float><<<dim3((rowsc + 127) / 128, 4), 256, 0, stream>>>(
                Uf16, b_f, h16, c_lvl, fc_lvl, lc, rowsc);
            level_kernel<float><<<dim3((rowsp + 127) / 128, 4), 256, 0, stream>>>(
                Uiou16, b_iou, h16, c_lvl, fc_lvl, l, rowsp);
        }
    } else {
        f16* c_lvl  = (f16*)c_buf;
        f16* fc_lvl = (f16*)fc_buf;
        leaf_kernel<f16><<<dim3(512, 4), 256, 0, stream>>>(
            x, Emb, Wiou16, b_iou, h16, c_lvl);
        for (int l = 10; l >= 0; --l) {
            int lc = l + 1;
            int rowsc = B_TREES << lc;
            int rowsp = B_TREES << l;
            fgate_kernel<f16><<<dim3((rowsc + 127) / 128, 4), 256, 0, stream>>>(
                Uf16, b_f, h16, c_lvl, fc_lvl, lc, rowsc);
            level_kernel<f16><<<dim3((rowsp + 127) / 128, 4), 256, 0, stream>>>(
                Uiou16, b_iou, h16, c_lvl, fc_lvl, l, rowsp);
        }
    }

    out_kernel<<<(N_NODES + 255) / 256, 256, 0, stream>>>(h16, W_out, b_out, out);
}

// Round 3
// 835.259 us; speedup vs baseline: 1.2401x; 1.2401x over previous
//
#include <hip/hip_runtime.h>

// Problem constants (from reference)
#define B_TREES 32
#define DEPTH   12
#define M_NODES 4095                  // 2^12 - 1
#define N_NODES (B_TREES * M_NODES)   // 131040
#define HDIM    256
#define VOCAB   32000
#define NCLS    20
#define MAXROWS 65536                 // largest level (leaves): 32 * 2048

typedef _Float16 f16;
typedef _Float16 f16x8 __attribute__((ext_vector_type(8)));
typedef _Float16 f16x4 __attribute__((ext_vector_type(4)));
typedef float    f32x4 __attribute__((ext_vector_type(4)));

__device__ __forceinline__ float sigf(float x)      { return 1.0f / (1.0f + __expf(-x)); }
__device__ __forceinline__ float tanh_fast(float x) { return 1.0f - 2.0f / (1.0f + __expf(2.0f * x)); }

// ---------------------------------------------------------------------------
// Init: convert weight matrices to fp16. W_out padded to 32 rows (zeros).
// ---------------------------------------------------------------------------
__global__ __launch_bounds__(256) void cvt_kernel(
    const float4* __restrict__ Wiou, const float4* __restrict__ Uiou,
    const float4* __restrict__ Uf,   const float4* __restrict__ Wout,
    f16x4* __restrict__ Wiou16, f16x4* __restrict__ Uiou16,
    f16x4* __restrict__ Uf16,   f16x4* __restrict__ Wout16)
{
    int i = blockIdx.x * 256 + threadIdx.x;   // in units of 4 floats
    if (i < 768 * HDIM / 4) {
        float4 v = Wiou[i];
        f16x4 r; r[0] = (f16)v.x; r[1] = (f16)v.y; r[2] = (f16)v.z; r[3] = (f16)v.w;
        Wiou16[i] = r;
        float4 u = Uiou[i];
        f16x4 s; s[0] = (f16)u.x; s[1] = (f16)u.y; s[2] = (f16)u.z; s[3] = (f16)u.w;
        Uiou16[i] = s;
    }
    if (i < HDIM * HDIM / 4) {
        float4 v = Uf[i];
        f16x4 r; r[0] = (f16)v.x; r[1] = (f16)v.y; r[2] = (f16)v.z; r[3] = (f16)v.w;
        Uf16[i] = r;
    }
    if (i < 32 * HDIM / 4) {                  // 32 padded rows of W_out
        int row = i >> 6;                     // / (HDIM/4)
        f16x4 r = {};
        if (row < NCLS) {
            float4 v = Wout[i];
            r[0] = (f16)v.x; r[1] = (f16)v.y; r[2] = (f16)v.z; r[3] = (f16)v.w;
        }
        Wout16[i] = r;
    }
}

// ---------------------------------------------------------------------------
// Leaf kernel: xiou = Emb[x] @ Wiou16^T (+b_iou), fused gate epilogue.
// 65536 leaf rows, 512 blocks x 128 rows. A-fragments for the whole K=256
// are gathered ONCE into registers (64 VGPRs), then the 4 column blocks are
// computed in-block (kills the 4x embedding re-gather of round 2).
// ---------------------------------------------------------------------------
__global__ __launch_bounds__(256) void leaf_kernel(
    const int* __restrict__ x, const float* __restrict__ Emb,
    const f16* __restrict__ Wiou16, const float* __restrict__ b_iou,
    f16* __restrict__ h16, float* __restrict__ c_lvl)
{
    const int lane = threadIdx.x & 63;
    const int w    = threadIdx.x >> 6;
    const int r0   = blockIdx.x * 128;
    const int qk   = (lane >> 4) * 8;
    const int l15  = lane & 15;

    int embBase[2];
    #pragma unroll
    for (int rf = 0; rf < 2; ++rf) {
        int row  = r0 + w * 32 + rf * 16 + l15;       // < 65536 (grid exact)
        int b    = row >> 11, t = row & 2047;
        int node = b * M_NODES + 2047 + t;
        embBase[rf] = x[node] * HDIM;
    }

    // Gather + convert A fragments for all K once.
    f16x8 a[8][2];
    #pragma unroll
    for (int ks = 0; ks < 8; ++ks) {
        const int k0 = ks * 32 + qk;
        #pragma unroll
        for (int rf = 0; rf < 2; ++rf) {
            float4 v0 = *(const float4*)(Emb + embBase[rf] + k0);
            float4 v1 = *(const float4*)(Emb + embBase[rf] + k0 + 4);
            f16x8 av;
            av[0] = (f16)v0.x; av[1] = (f16)v0.y; av[2] = (f16)v0.z; av[3] = (f16)v0.w;
            av[4] = (f16)v1.x; av[5] = (f16)v1.y; av[6] = (f16)v1.z; av[7] = (f16)v1.w;
            a[ks][rf] = av;
        }
    }

    for (int cb = 0; cb < 4; ++cb) {
        const int cb0 = cb * 64;
        int wBase[3][4];
        #pragma unroll
        for (int mat = 0; mat < 3; ++mat)
            #pragma unroll
            for (int cf = 0; cf < 4; ++cf)
                wBase[mat][cf] = (mat * 256 + cb0 + cf * 16 + l15) * HDIM;

        f32x4 acc[3][2][4] = {};
        #pragma unroll
        for (int ks = 0; ks < 8; ++ks) {
            const int k0 = ks * 32 + qk;
            f16x8 bf[3][4];
            #pragma unroll
            for (int mat = 0; mat < 3; ++mat)
                #pragma unroll
                for (int cf = 0; cf < 4; ++cf)
                    bf[mat][cf] = *(const f16x8*)(Wiou16 + wBase[mat][cf] + k0);
            #pragma unroll
            for (int mat = 0; mat < 3; ++mat)
                #pragma unroll
                for (int rf = 0; rf < 2; ++rf)
                    #pragma unroll
                    for (int cf = 0; cf < 4; ++cf)
                        acc[mat][rf][cf] = __builtin_amdgcn_mfma_f32_16x16x32_f16(
                            a[ks][rf], bf[mat][cf], acc[mat][rf][cf], 0, 0, 0);
        }

        // Epilogue: leaves have h_sum = 0, fc_sum = 0.
        #pragma unroll
        for (int rf = 0; rf < 2; ++rf) {
            const int rbase = r0 + w * 32 + rf * 16 + (lane >> 4) * 4;
            #pragma unroll
            for (int cf = 0; cf < 4; ++cf) {
                const int col = cb0 + cf * 16 + l15;
                const float bi = b_iou[col], bo = b_iou[256 + col], bu = b_iou[512 + col];
                #pragma unroll
                for (int r = 0; r < 4; ++r) {
                    int row  = rbase + r;                  // leaf-local row
                    int b    = row >> 11, t = row & 2047;
                    int node = b * M_NODES + 2047 + t;
                    float i_ = acc[0][rf][cf][r] + bi;
                    float o_ = acc[1][rf][cf][r] + bo;
                    float u_ = acc[2][rf][cf][r] + bu;
                    float c  = sigf(i_) * tanh_fast(u_);
                    float h  = sigf(o_) * tanh_fast(c);
                    c_lvl[row * HDIM + col]  = c;
                    h16[node * HDIM + col]   = (f16)h;
                }
            }
        }
    }
}

// ---------------------------------------------------------------------------
// Fused level kernel (parent level l, child level lc=l+1), 128 parents x 64
// cols per block:
//   Phase 1: f = sig(h_child @ Uf^T + b_f) for the block's 256 children,
//            fc pair-sum -> LDS tile fcs[128][64] (fp32).
//   Phase 2: iou = (h[2p]+h[2p+1]) @ Uiou^T + b_iou,
//            c = sig(i)*tanh(u) + fcs, h = sig(o)*tanh(c).
// c buffers are level-local row indexed and ping-pong between levels.
// ---------------------------------------------------------------------------
#define FCS_STRIDE 68
__global__ __launch_bounds__(256) void fused_level_kernel(
    const f16* __restrict__ Uiou16, const f16* __restrict__ Uf16,
    const float* __restrict__ b_iou, const float* __restrict__ b_f,
    f16* __restrict__ h16, const float* __restrict__ c_child,
    float* __restrict__ c_parent, int l, int rows_p)
{
    __shared__ float fcs[128 * FCS_STRIDE];   // 34.8 KB

    const int lane = threadIdx.x & 63;
    const int w    = threadIdx.x >> 6;
    const int quad = lane >> 4;
    const int r0   = blockIdx.x * 128;        // first parent row of block
    const int cb0  = blockIdx.y * 64;
    const int qk   = quad * 8;
    const int l15  = lane & 15;
    const int lc   = l + 1;
    const int maskc  = (1 << lc) - 1;
    const int rows_c = rows_p * 2;

    // ---------------- Phase 1: forget gates on 256 children ----------------
    {
        int childBase[4];
        #pragma unroll
        for (int rf = 0; rf < 4; ++rf) {
            int cl = 2 * r0 + w * 64 + rf * 16 + l15;
            if (cl >= rows_c) cl = rows_c - 1;
            int node = (cl >> lc) * M_NODES + maskc + (cl & maskc);
            childBase[rf] = node * HDIM;
        }
        int wBaseF[4];
        #pragma unroll
        for (int cf = 0; cf < 4; ++cf)
            wBaseF[cf] = (cb0 + cf * 16 + l15) * HDIM;

        f32x4 accf[4][4] = {};
        #pragma unroll
        for (int ks = 0; ks < 8; ++ks) {
            const int k0 = ks * 32 + qk;
            f16x8 a[4], bf[4];
            #pragma unroll
            for (int rf = 0; rf < 4; ++rf)
                a[rf] = *(const f16x8*)(h16 + childBase[rf] + k0);
            #pragma unroll
            for (int cf = 0; cf < 4; ++cf)
                bf[cf] = *(const f16x8*)(Uf16 + wBaseF[cf] + k0);
            #pragma unroll
            for (int rf = 0; rf < 4; ++rf)
                #pragma unroll
                for (int cf = 0; cf < 4; ++cf)
                    accf[rf][cf] = __builtin_amdgcn_mfma_f32_16x16x32_f16(
                        a[rf], bf[cf], accf[rf][cf], 0, 0, 0);
        }

        #pragma unroll
        for (int rf = 0; rf < 4; ++rf) {
            const int rbase = 2 * r0 + w * 64 + rf * 16 + quad * 4;  // even
            #pragma unroll
            for (int cf = 0; cf < 4; ++cf) {
                const int col = cb0 + cf * 16 + l15;
                const float bfv = b_f[col];
                #pragma unroll
                for (int pr = 0; pr < 2; ++pr) {
                    int cl0 = rbase + 2 * pr;          // even child row
                    if (cl0 < rows_c) {                // pair valid together
                        float f0 = sigf(accf[rf][cf][2 * pr]     + bfv);
                        float f1 = sigf(accf[rf][cf][2 * pr + 1] + bfv);
                        float fc = f0 * c_child[cl0 * HDIM + col]
                                 + f1 * c_child[(cl0 + 1) * HDIM + col];
                        int p_blk = (cl0 >> 1) - r0;   // [0,128)
                        fcs[p_blk * FCS_STRIDE + cf * 16 + l15] = fc;
                    }
                }
            }
        }
    }
    __syncthreads();

    // ---------------- Phase 2: iou GEMM on child-sum h ----------------
    const int maskp = (1 << l) - 1;
    int pChildBase[2];
    #pragma unroll
    for (int rf = 0; rf < 2; ++rf) {
        int p = r0 + w * 32 + rf * 16 + l15;
        if (p >= rows_p) p = rows_p - 1;
        int b = p >> l, t = p & maskp;
        int c1 = b * M_NODES + (2 << l) - 1 + 2 * t;   // left child node
        pChildBase[rf] = c1 * HDIM;
    }
    int wBase[3][4];
    #pragma unroll
    for (int mat = 0; mat < 3; ++mat)
        #pragma unroll
        for (int cf = 0; cf < 4; ++cf)
            wBase[mat][cf] = (mat * 256 + cb0 + cf * 16 + l15) * HDIM;

    f32x4 acc[3][2][4] = {};
    #pragma unroll
    for (int ks = 0; ks < 8; ++ks) {
        const int k0 = ks * 32 + qk;
        f16x8 a[2], bf[3][4];
        #pragma unroll
        for (int rf = 0; rf < 2; ++rf) {
            f16x8 a1 = *(const f16x8*)(h16 + pChildBase[rf] + k0);
            f16x8 a2 = *(const f16x8*)(h16 + pChildBase[rf] + HDIM + k0);
            a[rf] = a1 + a2;                           // child-sum of h
        }
        #pragma unroll
        for (int mat = 0; mat < 3; ++mat)
            #pragma unroll
            for (int cf = 0; cf < 4; ++cf)
                bf[mat][cf] = *(const f16x8*)(Uiou16 + wBase[mat][cf] + k0);
        #pragma unroll
        for (int mat = 0; mat < 3; ++mat)
            #pragma unroll
            for (int rf = 0; rf < 2; ++rf)
                #pragma unroll
                for (int cf = 0; cf < 4; ++cf)
                    acc[mat][rf][cf] = __builtin_amdgcn_mfma_f32_16x16x32_f16(
                        a[rf], bf[mat][cf], acc[mat][rf][cf], 0, 0, 0);
    }

    #pragma unroll
    for (int rf = 0; rf < 2; ++rf) {
        const int rbase = r0 + w * 32 + rf * 16 + quad * 4;
        #pragma unroll
        for (int cf = 0; cf < 4; ++cf) {
            const int col = cb0 + cf * 16 + l15;
            const float bi = b_iou[col], bo = b_iou[256 + col], bu = b_iou[512 + col];
            #pragma unroll
            for (int r = 0; r < 4; ++r) {
                int p = rbase + r;                     // parent level-local row
                if (p < rows_p) {
                    int b = p >> l, t = p & maskp;
                    int node = b * M_NODES + (1 << l) - 1 + t;
                    float fcv = fcs[(p - r0) * FCS_STRIDE + cf * 16 + l15];
                    float i_ = acc[0][rf][cf][r] + bi;
                    float o_ = acc[1][rf][cf][r] + bo;
                    float u_ = acc[2][rf][cf][r] + bu;
                    float c  = sigf(i_) * tanh_fast(u_) + fcv;
                    float h  = sigf(o_) * tanh_fast(c);
                    c_parent[p * HDIM + col] = c;
                    h16[node * HDIM + col]   = (f16)h;
                }
            }
        }
    }
}

// ---------------------------------------------------------------------------
// Output: out = h_all @ W_out^T + b_out, MFMA with N padded 20->32.
// 1024 blocks x 128 rows.
// ---------------------------------------------------------------------------
__global__ __launch_bounds__(256) void out_kernel(
    const f16* __restrict__ h16, const f16* __restrict__ Wout16,
    const float* __restrict__ bout, float* __restrict__ out)
{
    const int lane = threadIdx.x & 63;
    const int w    = threadIdx.x >> 6;
    const int quad = lane >> 4;
    const int r0   = blockIdx.x * 128;
    const int qk   = quad * 8;
    const int l15  = lane & 15;

    int rowBase[2];
    #pragma unroll
    for (int rf = 0; rf < 2; ++rf) {
        int row = r0 + w * 32 + rf * 16 + l15;
        if (row >= N_NODES) row = N_NODES - 1;
        rowBase[rf] = row * HDIM;
    }
    int wB[2];
    #pragma unroll
    for (int cf = 0; cf < 2; ++cf)
        wB[cf] = (cf * 16 + l15) * HDIM;

    f32x4 acc[2][2] = {};
    #pragma unroll
    for (int ks = 0; ks < 8; ++ks) {
        const int k0 = ks * 32 + qk;
        f16x8 a[2], bf[2];
        #pragma unroll
        for (int rf = 0; rf < 2; ++rf)
            a[rf] = *(const f16x8*)(h16 + rowBase[rf] + k0);
        #pragma unroll
        for (int cf = 0; cf < 2; ++cf)
            bf[cf] = *(const f16x8*)(Wout16 + wB[cf] + k0);
        #pragma unroll
        for (int rf = 0; rf < 2; ++rf)
            #pragma unroll
            for (int cf = 0; cf < 2; ++cf)
                acc[rf][cf] = __builtin_amdgcn_mfma_f32_16x16x32_f16(
                    a[rf], bf[cf], acc[rf][cf], 0, 0, 0);
    }

    #pragma unroll
    for (int rf = 0; rf < 2; ++rf) {
        const int rbase = r0 + w * 32 + rf * 16 + quad * 4;
        #pragma unroll
        for (int cf = 0; cf < 2; ++cf) {
            const int col = cf * 16 + l15;
            if (col < NCLS) {
                const float bo = bout[col];
                #pragma unroll
                for (int r = 0; r < 4; ++r) {
                    int row = rbase + r;
                    if (row < N_NODES)
                        out[row * NCLS + col] = acc[rf][cf][r] + bo;
                }
            }
        }
    }
}

// ---------------------------------------------------------------------------
extern "C" void kernel_launch(void* const* d_in, const int* in_sizes, int n_in,
                              void* d_out, int out_size, void* d_ws, size_t ws_size,
                              hipStream_t stream)
{
    const int*   x     = (const int*)d_in[0];
    // d_in[1] = x_mask: leaf structure is static — folded into indexing.
    const float* Emb   = (const float*)d_in[2];
    const float* W_iou = (const float*)d_in[3];
    const float* b_iou = (const float*)d_in[4];
    const float* U_iou = (const float*)d_in[5];
    const float* U_f   = (const float*)d_in[6];
    const float* b_f   = (const float*)d_in[7];
    const float* W_out = (const float*)d_in[8];
    const float* b_out = (const float*)d_in[9];
    float* out = (float*)d_out;

    // Workspace: h16 67.1 + cA 67.1 + cB 33.6 + weights ~0.9 MB = ~169 MB.
    // (Round-2 fp32 path used ~202 MB and fit, so no fallback needed.)
    char* ws = (char*)d_ws;
    size_t off = 0;
    auto take = [&](size_t bytes) -> char* {
        char* p = ws + off; off += (bytes + 255) & ~(size_t)255; return p;
    };
    f16*   h16    = (f16*)take((size_t)N_NODES * HDIM * 2);
    float* cA     = (float*)take((size_t)MAXROWS * HDIM * 4);        // 65536 rows
    float* cB     = (float*)take((size_t)(MAXROWS / 2) * HDIM * 4);  // 32768 rows
    f16*   Wiou16 = (f16*)take((size_t)768 * HDIM * 2);
    f16*   Uiou16 = (f16*)take((size_t)768 * HDIM * 2);
    f16*   Uf16   = (f16*)take((size_t)HDIM * HDIM * 2);
    f16*   Wout16 = (f16*)take((size_t)32 * HDIM * 2);

    cvt_kernel<<<768 * HDIM / 4 / 256, 256, 0, stream>>>(
        (const float4*)W_iou, (const float4*)U_iou, (const float4*)U_f,
        (const float4*)W_out,
        (f16x4*)Wiou16, (f16x4*)Uiou16, (f16x4*)Uf16, (f16x4*)Wout16);

    // Leaves (level 11): 65536 rows, c -> cA
    leaf_kernel<<<dim3(512), 256, 0, stream>>>(x, Emb, Wiou16, b_iou, h16, cA);

    // Levels 10..0, fused fgate+level, ping-pong c buffers
    float* cin  = cA;
    float* cout_ = cB;
    for (int l = 10; l >= 0; --l) {
        int rows_p = B_TREES << l;
        fused_level_kernel<<<dim3((rows_p + 127) / 128, 4), 256, 0, stream>>>(
            Uiou16, Uf16, b_iou, b_f, h16, cin, cout_, l, rows_p);
        float* t = cin; cin = cout_; cout_ = t;
    }

    out_kernel<<<dim3((N_NODES + 127) / 128), 256, 0, stream>>>(
        h16, Wout16, b_out, out);
}

// Round 4
// 753.037 us; speedup vs baseline: 1.3755x; 1.1092x over previous
//
#include <hip/hip_runtime.h>

// Problem constants (from reference)
#define B_TREES 32
#define DEPTH   12
#define M_NODES 4095                  // 2^12 - 1
#define N_NODES (B_TREES * M_NODES)   // 131040
#define HDIM    256
#define VOCAB   32000
#define NCLS    20
#define LEAFROWS 65536                // 32 * 2048 leaves

typedef _Float16 f16;
typedef _Float16 f16x8 __attribute__((ext_vector_type(8)));
typedef _Float16 f16x4 __attribute__((ext_vector_type(4)));
typedef float    f32x4 __attribute__((ext_vector_type(4)));

__device__ __forceinline__ float sigf(float x)      { return 1.0f / (1.0f + __expf(-x)); }
__device__ __forceinline__ float tanh_fast(float x) { return 1.0f - 2.0f / (1.0f + __expf(2.0f * x)); }

// ---------------------------------------------------------------------------
// Init: convert Emb + weights to fp16. W_out padded to 32 rows (zeros).
// Grid covers VOCAB*HDIM/4 elements (8000 blocks).
// ---------------------------------------------------------------------------
__global__ __launch_bounds__(256) void cvt_kernel(
    const float4* __restrict__ Emb,  const float4* __restrict__ Wiou,
    const float4* __restrict__ Uiou, const float4* __restrict__ Uf,
    const float4* __restrict__ Wout,
    f16x4* __restrict__ Emb16,  f16x4* __restrict__ Wiou16,
    f16x4* __restrict__ Uiou16, f16x4* __restrict__ Uf16,
    f16x4* __restrict__ Wout16)
{
    int i = blockIdx.x * 256 + threadIdx.x;   // in units of 4 floats
    if (i < VOCAB * HDIM / 4) {
        float4 v = Emb[i];
        f16x4 r; r[0] = (f16)v.x; r[1] = (f16)v.y; r[2] = (f16)v.z; r[3] = (f16)v.w;
        Emb16[i] = r;
    }
    if (i < 768 * HDIM / 4) {
        float4 v = Wiou[i];
        f16x4 r; r[0] = (f16)v.x; r[1] = (f16)v.y; r[2] = (f16)v.z; r[3] = (f16)v.w;
        Wiou16[i] = r;
        float4 u = Uiou[i];
        f16x4 s; s[0] = (f16)u.x; s[1] = (f16)u.y; s[2] = (f16)u.z; s[3] = (f16)u.w;
        Uiou16[i] = s;
    }
    if (i < HDIM * HDIM / 4) {
        float4 v = Uf[i];
        f16x4 r; r[0] = (f16)v.x; r[1] = (f16)v.y; r[2] = (f16)v.z; r[3] = (f16)v.w;
        Uf16[i] = r;
    }
    if (i < 32 * HDIM / 4) {                  // 32 padded rows of W_out
        int row = i >> 6;
        f16x4 r = {};
        if (row < NCLS) {
            float4 v = Wout[i];
            r[0] = (f16)v.x; r[1] = (f16)v.y; r[2] = (f16)v.z; r[3] = (f16)v.w;
        }
        Wout16[i] = r;
    }
}

// ---------------------------------------------------------------------------
// Leaf kernel: xiou = Emb16[x] @ Wiou16^T (+b_iou), fused gate epilogue.
// 512 blocks x 128 rows; A fragments for whole K held in regs; 4 col-blocks
// in-block. c written TRANSPOSED f16: cT[col * 65536 + row]. h written via
// LDS transpose tile -> coalesced f16x8 global stores.
// ---------------------------------------------------------------------------
#define HT_STRIDE 68
__global__ __launch_bounds__(256) void leaf_kernel(
    const int* __restrict__ x, const f16* __restrict__ Emb16,
    const f16* __restrict__ Wiou16, const float* __restrict__ b_iou,
    f16* __restrict__ h16, f16* __restrict__ cT)
{
    __shared__ f16 ldsh[128 * HT_STRIDE];     // 17.4 KB

    const int lane = threadIdx.x & 63;
    const int w    = threadIdx.x >> 6;
    const int quad = lane >> 4;
    const int r0   = blockIdx.x * 128;
    const int qk   = quad * 8;
    const int l15  = lane & 15;

    int embBase[2];
    #pragma unroll
    for (int rf = 0; rf < 2; ++rf) {
        int row  = r0 + w * 32 + rf * 16 + l15;       // < 65536 (grid exact)
        int b    = row >> 11, t = row & 2047;
        int node = b * M_NODES + 2047 + t;
        embBase[rf] = x[node] * HDIM;
    }

    // Gather A fragments for all K once (f16 table).
    f16x8 a[8][2];
    #pragma unroll
    for (int ks = 0; ks < 8; ++ks) {
        const int k0 = ks * 32 + qk;
        #pragma unroll
        for (int rf = 0; rf < 2; ++rf)
            a[ks][rf] = *(const f16x8*)(Emb16 + embBase[rf] + k0);
    }

    // node base for this block's rows (contiguous: same tree within block)
    const int node0 = (r0 >> 11) * M_NODES + 2047 + (r0 & 2047);

    for (int cb = 0; cb < 4; ++cb) {
        const int cb0 = cb * 64;
        int wBase[3][4];
        #pragma unroll
        for (int mat = 0; mat < 3; ++mat)
            #pragma unroll
            for (int cf = 0; cf < 4; ++cf)
                wBase[mat][cf] = (mat * 256 + cb0 + cf * 16 + l15) * HDIM;

        f32x4 acc[3][2][4] = {};
        #pragma unroll
        for (int ks = 0; ks < 8; ++ks) {
            const int k0 = ks * 32 + qk;
            f16x8 bf[3][4];
            #pragma unroll
            for (int mat = 0; mat < 3; ++mat)
                #pragma unroll
                for (int cf = 0; cf < 4; ++cf)
                    bf[mat][cf] = *(const f16x8*)(Wiou16 + wBase[mat][cf] + k0);
            #pragma unroll
            for (int mat = 0; mat < 3; ++mat)
                #pragma unroll
                for (int rf = 0; rf < 2; ++rf)
                    #pragma unroll
                    for (int cf = 0; cf < 4; ++cf)
                        acc[mat][rf][cf] = __builtin_amdgcn_mfma_f32_16x16x32_f16(
                            a[ks][rf], bf[mat][cf], acc[mat][rf][cf], 0, 0, 0);
        }

        if (cb) __syncthreads();   // protect ldsh reuse from previous cb
        // Epilogue: leaves have h_sum = 0, fc_sum = 0.
        #pragma unroll
        for (int rf = 0; rf < 2; ++rf) {
            const int rbase = r0 + w * 32 + rf * 16 + quad * 4;
            #pragma unroll
            for (int cf = 0; cf < 4; ++cf) {
                const int col = cb0 + cf * 16 + l15;
                const float bi = b_iou[col], bo = b_iou[256 + col], bu = b_iou[512 + col];
                f16x4 cv;
                #pragma unroll
                for (int r = 0; r < 4; ++r) {
                    float i_ = acc[0][rf][cf][r] + bi;
                    float o_ = acc[1][rf][cf][r] + bo;
                    float u_ = acc[2][rf][cf][r] + bu;
                    float c  = sigf(i_) * tanh_fast(u_);
                    float h  = sigf(o_) * tanh_fast(c);
                    cv[r] = (f16)c;
                    ldsh[(rbase - r0 + r) * HT_STRIDE + (col - cb0)] = (f16)h;
                }
                *(f16x4*)(cT + col * LEAFROWS + rbase) = cv;
            }
        }
        __syncthreads();
        // Drain ldsh -> h16 (coalesced 16B stores)
        #pragma unroll
        for (int t = 0; t < 4; ++t) {
            int idx   = threadIdx.x + t * 256;     // 0..1023
            int row_l = idx >> 3, chunk = idx & 7;
            f16x8 v = *(const f16x8*)(ldsh + row_l * HT_STRIDE + chunk * 8);
            *(f16x8*)(h16 + (node0 + row_l) * HDIM + cb0 + chunk * 8) = v;
        }
    }
}

// ---------------------------------------------------------------------------
// Fused level kernel (parent level l): phase 1 = forget gates on children +
// fc pair-sum into LDS; phase 2 = iou GEMM on child-sum h + gate epilogue.
// c buffers transposed f16 [col][row], strides rows_c / rows_p.
// ---------------------------------------------------------------------------
#define FCS_STRIDE 68
__global__ __launch_bounds__(256) void fused_level_kernel(
    const f16* __restrict__ Uiou16, const f16* __restrict__ Uf16,
    const float* __restrict__ b_iou, const float* __restrict__ b_f,
    f16* __restrict__ h16, const f16* __restrict__ cT_child,
    f16* __restrict__ cT_parent, int l, int rows_p)
{
    __shared__ float fcs[128 * FCS_STRIDE];   // 34.8 KB
    __shared__ f16   ldsh[128 * HT_STRIDE];   // 17.4 KB

    const int lane = threadIdx.x & 63;
    const int w    = threadIdx.x >> 6;
    const int quad = lane >> 4;
    const int r0   = blockIdx.x * 128;        // first parent row of block
    const int cb0  = blockIdx.y * 64;
    const int qk   = quad * 8;
    const int l15  = lane & 15;
    const int lc   = l + 1;
    const int maskc  = (1 << lc) - 1;
    const int rows_c = rows_p * 2;

    // ---------------- Phase 1: forget gates on 256 children ----------------
    {
        // Hoist c_child loads (independent of the GEMM): 16 x 8B vector loads
        f16x4 cc[4][4];
        bool  valid[4];
        #pragma unroll
        for (int rf = 0; rf < 4; ++rf) {
            int R0 = 2 * r0 + w * 64 + rf * 16 + quad * 4;
            valid[rf] = (R0 < rows_c);
            int R = valid[rf] ? R0 : (rows_c - 4);
            #pragma unroll
            for (int cf = 0; cf < 4; ++cf) {
                const int col = cb0 + cf * 16 + l15;
                cc[rf][cf] = *(const f16x4*)(cT_child + col * rows_c + R);
            }
        }

        int childBase[4];
        #pragma unroll
        for (int rf = 0; rf < 4; ++rf) {
            int cl = 2 * r0 + w * 64 + rf * 16 + l15;
            if (cl >= rows_c) cl = rows_c - 1;
            int node = (cl >> lc) * M_NODES + maskc + (cl & maskc);
            childBase[rf] = node * HDIM;
        }
        int wBaseF[4];
        #pragma unroll
        for (int cf = 0; cf < 4; ++cf)
            wBaseF[cf] = (cb0 + cf * 16 + l15) * HDIM;

        f32x4 accf[4][4] = {};
        #pragma unroll
        for (int ks = 0; ks < 8; ++ks) {
            const int k0 = ks * 32 + qk;
            f16x8 a[4], bf[4];
            #pragma unroll
            for (int rf = 0; rf < 4; ++rf)
                a[rf] = *(const f16x8*)(h16 + childBase[rf] + k0);
            #pragma unroll
            for (int cf = 0; cf < 4; ++cf)
                bf[cf] = *(const f16x8*)(Uf16 + wBaseF[cf] + k0);
            #pragma unroll
            for (int rf = 0; rf < 4; ++rf)
                #pragma unroll
                for (int cf = 0; cf < 4; ++cf)
                    accf[rf][cf] = __builtin_amdgcn_mfma_f32_16x16x32_f16(
                        a[rf], bf[cf], accf[rf][cf], 0, 0, 0);
        }

        #pragma unroll
        for (int rf = 0; rf < 4; ++rf) {
            if (valid[rf]) {
                const int R0 = 2 * r0 + w * 64 + rf * 16 + quad * 4;
                #pragma unroll
                for (int cf = 0; cf < 4; ++cf) {
                    const int col = cb0 + cf * 16 + l15;
                    const float bfv = b_f[col];
                    #pragma unroll
                    for (int pr = 0; pr < 2; ++pr) {
                        float f0 = sigf(accf[rf][cf][2 * pr]     + bfv);
                        float f1 = sigf(accf[rf][cf][2 * pr + 1] + bfv);
                        float fc = f0 * (float)cc[rf][cf][2 * pr]
                                 + f1 * (float)cc[rf][cf][2 * pr + 1];
                        int p_blk = (R0 >> 1) + pr - r0;   // [0,128)
                        fcs[p_blk * FCS_STRIDE + cf * 16 + l15] = fc;
                    }
                }
            }
        }
    }
    __syncthreads();

    // ---------------- Phase 2: iou GEMM on child-sum h ----------------
    const int maskp = (1 << l) - 1;
    int pChildBase[2];
    #pragma unroll
    for (int rf = 0; rf < 2; ++rf) {
        int p = r0 + w * 32 + rf * 16 + l15;
        if (p >= rows_p) p = rows_p - 1;
        int b = p >> l, t = p & maskp;
        int c1 = b * M_NODES + (2 << l) - 1 + 2 * t;   // left child node
        pChildBase[rf] = c1 * HDIM;
    }
    int wBase[3][4];
    #pragma unroll
    for (int mat = 0; mat < 3; ++mat)
        #pragma unroll
        for (int cf = 0; cf < 4; ++cf)
            wBase[mat][cf] = (mat * 256 + cb0 + cf * 16 + l15) * HDIM;

    f32x4 acc[3][2][4] = {};
    #pragma unroll
    for (int ks = 0; ks < 8; ++ks) {
        const int k0 = ks * 32 + qk;
        f16x8 a[2], bf[3][4];
        #pragma unroll
        for (int rf = 0; rf < 2; ++rf) {
            f16x8 a1 = *(const f16x8*)(h16 + pChildBase[rf] + k0);
            f16x8 a2 = *(const f16x8*)(h16 + pChildBase[rf] + HDIM + k0);
            a[rf] = a1 + a2;                           // child-sum of h
        }
        #pragma unroll
        for (int mat = 0; mat < 3; ++mat)
            #pragma unroll
            for (int cf = 0; cf < 4; ++cf)
                bf[mat][cf] = *(const f16x8*)(Uiou16 + wBase[mat][cf] + k0);
        #pragma unroll
        for (int mat = 0; mat < 3; ++mat)
            #pragma unroll
            for (int rf = 0; rf < 2; ++rf)
                #pragma unroll
                for (int cf = 0; cf < 4; ++cf)
                    acc[mat][rf][cf] = __builtin_amdgcn_mfma_f32_16x16x32_f16(
                        a[rf], bf[mat][cf], acc[mat][rf][cf], 0, 0, 0);
    }

    #pragma unroll
    for (int rf = 0; rf < 2; ++rf) {
        const int Pb = r0 + w * 32 + rf * 16 + quad * 4;
        const bool pv = (Pb < rows_p);
        #pragma unroll
        for (int cf = 0; cf < 4; ++cf) {
            const int col = cb0 + cf * 16 + l15;
            const float bi = b_iou[col], bo = b_iou[256 + col], bu = b_iou[512 + col];
            f16x4 cv;
            #pragma unroll
            for (int r = 0; r < 4; ++r) {
                float fcv = fcs[(Pb - r0 + r) * FCS_STRIDE + cf * 16 + l15];
                float i_ = acc[0][rf][cf][r] + bi;
                float o_ = acc[1][rf][cf][r] + bo;
                float u_ = acc[2][rf][cf][r] + bu;
                float c  = sigf(i_) * tanh_fast(u_) + fcv;
                float h  = sigf(o_) * tanh_fast(c);
                cv[r] = (f16)c;
                if (pv) ldsh[(Pb - r0 + r) * HT_STRIDE + (col - cb0)] = (f16)h;
            }
            if (pv) *(f16x4*)(cT_parent + col * rows_p + Pb) = cv;
        }
    }
    __syncthreads();
    // Drain ldsh -> h16 (coalesced 16B stores)
    const int vrows = (rows_p - r0 < 128) ? (rows_p - r0) : 128;
    #pragma unroll
    for (int t = 0; t < 4; ++t) {
        int idx   = threadIdx.x + t * 256;     // 0..1023
        int row_l = idx >> 3, chunk = idx & 7;
        if (row_l < vrows) {
            int p = r0 + row_l;
            int b = p >> l, tt = p & maskp;
            int node = b * M_NODES + (1 << l) - 1 + tt;
            f16x8 v = *(const f16x8*)(ldsh + row_l * HT_STRIDE + chunk * 8);
            *(f16x8*)(h16 + node * HDIM + cb0 + chunk * 8) = v;
        }
    }
}

// ---------------------------------------------------------------------------
// Output: out = h_all @ W_out^T + b_out, MFMA with N padded 20->32.
// ---------------------------------------------------------------------------
__global__ __launch_bounds__(256) void out_kernel(
    const f16* __restrict__ h16, const f16* __restrict__ Wout16,
    const float* __restrict__ bout, float* __restrict__ out)
{
    const int lane = threadIdx.x & 63;
    const int w    = threadIdx.x >> 6;
    const int quad = lane >> 4;
    const int r0   = blockIdx.x * 128;
    const int qk   = quad * 8;
    const int l15  = lane & 15;

    int rowBase[2];
    #pragma unroll
    for (int rf = 0; rf < 2; ++rf) {
        int row = r0 + w * 32 + rf * 16 + l15;
        if (row >= N_NODES) row = N_NODES - 1;
        rowBase[rf] = row * HDIM;
    }
    int wB[2];
    #pragma unroll
    for (int cf = 0; cf < 2; ++cf)
        wB[cf] = (cf * 16 + l15) * HDIM;

    f32x4 acc[2][2] = {};
    #pragma unroll
    for (int ks = 0; ks < 8; ++ks) {
        const int k0 = ks * 32 + qk;
        f16x8 a[2], bf[2];
        #pragma unroll
        for (int rf = 0; rf < 2; ++rf)
            a[rf] = *(const f16x8*)(h16 + rowBase[rf] + k0);
        #pragma unroll
        for (int cf = 0; cf < 2; ++cf)
            bf[cf] = *(const f16x8*)(Wout16 + wB[cf] + k0);
        #pragma unroll
        for (int rf = 0; rf < 2; ++rf)
            #pragma unroll
            for (int cf = 0; cf < 2; ++cf)
                acc[rf][cf] = __builtin_amdgcn_mfma_f32_16x16x32_f16(
                    a[rf], bf[cf], acc[rf][cf], 0, 0, 0);
    }

    #pragma unroll
    for (int rf = 0; rf < 2; ++rf) {
        const int rbase = r0 + w * 32 + rf * 16 + quad * 4;
        #pragma unroll
        for (int cf = 0; cf < 2; ++cf) {
            const int col = cf * 16 + l15;
            if (col < NCLS) {
                const float bo = bout[col];
                #pragma unroll
                for (int r = 0; r < 4; ++r) {
                    int row = rbase + r;
                    if (row < N_NODES)
                        out[row * NCLS + col] = acc[rf][cf][r] + bo;
                }
            }
        }
    }
}

// ---------------------------------------------------------------------------
extern "C" void kernel_launch(void* const* d_in, const int* in_sizes, int n_in,
                              void* d_out, int out_size, void* d_ws, size_t ws_size,
                              hipStream_t stream)
{
    const int*   x     = (const int*)d_in[0];
    // d_in[1] = x_mask: leaf structure is static — folded into indexing.
    const float* Emb   = (const float*)d_in[2];
    const float* W_iou = (const float*)d_in[3];
    const float* b_iou = (const float*)d_in[4];
    const float* U_iou = (const float*)d_in[5];
    const float* U_f   = (const float*)d_in[6];
    const float* b_f   = (const float*)d_in[7];
    const float* W_out = (const float*)d_in[8];
    const float* b_out = (const float*)d_in[9];
    float* out = (float*)d_out;

    // Workspace: h16 67.1 + cA 33.6 + cB 16.8 + Emb16 16.4 + weights ~1 MB
    // = ~135 MB (round-2's 202 MB fit, so safe).
    char* ws = (char*)d_ws;
    size_t off = 0;
    auto take = [&](size_t bytes) -> char* {
        char* p = ws + off; off += (bytes + 255) & ~(size_t)255; return p;
    };
    f16* h16    = (f16*)take((size_t)N_NODES * HDIM * 2);
    f16* cA     = (f16*)take((size_t)HDIM * LEAFROWS * 2);        // [256][65536]
    f16* cB     = (f16*)take((size_t)HDIM * (LEAFROWS / 2) * 2);  // [256][32768]
    f16* Emb16  = (f16*)take((size_t)VOCAB * HDIM * 2);
    f16* Wiou16 = (f16*)take((size_t)768 * HDIM * 2);
    f16* Uiou16 = (f16*)take((size_t)768 * HDIM * 2);
    f16* Uf16   = (f16*)take((size_t)HDIM * HDIM * 2);
    f16* Wout16 = (f16*)take((size_t)32 * HDIM * 2);

    cvt_kernel<<<VOCAB * HDIM / 4 / 256, 256, 0, stream>>>(
        (const float4*)Emb, (const float4*)W_iou, (const float4*)U_iou,
        (const float4*)U_f, (const float4*)W_out,
        (f16x4*)Emb16, (f16x4*)Wiou16, (f16x4*)Uiou16, (f16x4*)Uf16,
        (f16x4*)Wout16);

    // Leaves (level 11): 65536 rows, cT -> cA (stride 65536)
    leaf_kernel<<<dim3(512), 256, 0, stream>>>(x, Emb16, Wiou16, b_iou, h16, cA);

    // Levels 10..0, fused fgate+level, ping-pong transposed c buffers
    f16* cin  = cA;
    f16* cout_ = cB;
    for (int l = 10; l >= 0; --l) {
        int rows_p = B_TREES << l;
        fused_level_kernel<<<dim3((rows_p + 127) / 128, 4), 256, 0, stream>>>(
            Uiou16, Uf16, b_iou, b_f, h16, cin, cout_, l, rows_p);
        f16* t = cin; cin = cout_; cout_ = t;
    }

    out_kernel<<<dim3((N_NODES + 127) / 128), 256, 0, stream>>>(
        h16, Wout16, b_out, out);
}